// Round 4
// baseline (54.264 us; speedup 1.0000x reference)
//
#include <hip/hip_runtime.h>
#include <math.h>

#define H  1024
#define D2 2048   // input width of both big GEMVs
#define NBLK 256

typedef float f32x4 __attribute__((ext_vector_type(4)));

__device__ __forceinline__ float sigmoidf_(float x) {
    return 1.0f / (1.0f + expf(-x));
}

__device__ __forceinline__ float wave_sum(float v) {
#pragma unroll
    for (int off = 32; off >= 1; off >>= 1)
        v += __shfl_xor(v, off, 64);
    return v;
}

// Single fused kernel, 256 blocks x 256 threads (wave w of block b owns
// hidden index j = 4b+w for ALL stages). Custom spin barrier between the
// two LSTM layers; W_ih_1 rows register-prefetched (asm-pinned) before it.
// ws layout (bytes): [0..7] counters (memset to 0 per call by a graph node),
// [64..2111] pbuf (512 floats), [4096..12287] fin (2048 floats).
__global__ __launch_bounds__(256) void k_all(
    const float* __restrict__ x,      // map [2048]
    const float* __restrict__ Wm,     // W_ih_map [4096][2048]
    const float* __restrict__ bm_i,
    const float* __restrict__ bm_h,
    const float* __restrict__ Wp,     // W_ih_pts [4096][4]
    const float* __restrict__ bp_i,
    const float* __restrict__ bp_h,
    const float* __restrict__ W1,     // W_ih_1 [4096][2048]
    const float* __restrict__ b1_i,
    const float* __restrict__ b1_h,
    const float* __restrict__ goal,   // [2]
    const float* __restrict__ cur,    // [2]
    const float* __restrict__ fcw,    // [2][1024]
    const float* __restrict__ fcb,    // [2]
    unsigned*    __restrict__ cnt,    // ws: [0]=barrier, [1]=tail
    float*       __restrict__ pbuf,   // ws: 512 floats (per-block fc partials)
    float*       __restrict__ fing,   // ws: 2048 floats (final_in)
    float*       __restrict__ out)    // [2]
{
    const int tid  = threadIdx.x;
    const int wave = tid >> 6;
    const int lane = tid & 63;
    const int j    = blockIdx.x * 4 + wave;

    __shared__ float    finL[2048];
    __shared__ float    hs0[4], hs1[4];
    __shared__ unsigned slast;

    // ---- trivial points cell for this wave's j (lane 0 only)
    if (lane == 0) {
        float p0 = cur[0], p1 = cur[1], p2 = goal[0], p3 = goal[1];
        const f32x4* Wp4 = (const f32x4*)Wp;   // one f32x4 per row
        f32x4 wi = Wp4[j];
        f32x4 wg = Wp4[2 * H + j];
        f32x4 wo = Wp4[3 * H + j];
        float gi = wi.x * p0 + wi.y * p1 + wi.z * p2 + wi.w * p3 + bp_i[j] + bp_h[j];
        float gg = wg.x * p0 + wg.y * p1 + wg.z * p2 + wg.w * p3 + bp_i[2 * H + j] + bp_h[2 * H + j];
        float go = wo.x * p0 + wo.y * p1 + wo.z * p2 + wo.w * p3 + bp_i[3 * H + j] + bp_h[3 * H + j];
        float c = sigmoidf_(gi) * tanhf(gg);
        __hip_atomic_store(&fing[H + j], sigmoidf_(go) * tanhf(c),
                           __ATOMIC_RELAXED, __HIP_MEMORY_SCOPE_AGENT);
    }

    // ---- phase 1: map-cell GEMV row j (gates i, g, o), full-K per wave
    {
        const f32x4* x4 = (const f32x4*)x;
        const f32x4* Wi = (const f32x4*)(Wm + (size_t)j * D2);
        const f32x4* Wg = (const f32x4*)(Wm + (size_t)(2 * H + j) * D2);
        const f32x4* Wo = (const f32x4*)(Wm + (size_t)(3 * H + j) * D2);
        float si = 0.f, sg = 0.f, so = 0.f;
#pragma unroll
        for (int it = 0; it < 8; ++it) {
            int idx = it * 64 + lane;          // 512 f32x4 per row
            f32x4 xv = x4[idx];
            f32x4 a = Wi[idx];
            si += a.x * xv.x + a.y * xv.y + a.z * xv.z + a.w * xv.w;
            f32x4 g = Wg[idx];
            sg += g.x * xv.x + g.y * xv.y + g.z * xv.z + g.w * xv.w;
            f32x4 o = Wo[idx];
            so += o.x * xv.x + o.y * xv.y + o.z * xv.z + o.w * xv.w;
        }
        si = wave_sum(si);
        sg = wave_sum(sg);
        so = wave_sum(so);
        if (lane == 0) {
            float gi = si + bm_i[j] + bm_h[j];
            float gg = sg + bm_i[2 * H + j] + bm_h[2 * H + j];
            float go = so + bm_i[3 * H + j] + bm_h[3 * H + j];
            float c = sigmoidf_(gi) * tanhf(gg);
            __hip_atomic_store(&fing[j], sigmoidf_(go) * tanhf(c),
                               __ATOMIC_RELAXED, __HIP_MEMORY_SCOPE_AGENT);
        }
    }

    // ---- prefetch W_ih_1 rows for j into registers (fin-independent work
    //      that streams while other blocks finish phase 1)
    f32x4 rA[8], rG[8], rO[8];
    {
        const f32x4* Vi = (const f32x4*)(W1 + (size_t)j * D2);
        const f32x4* Vg = (const f32x4*)(W1 + (size_t)(2 * H + j) * D2);
        const f32x4* Vo = (const f32x4*)(W1 + (size_t)(3 * H + j) * D2);
#pragma unroll
        for (int it = 0; it < 8; ++it) {
            int idx = it * 64 + lane;
            rA[it] = Vi[idx];
            rG[it] = Vg[idx];
            rO[it] = Vo[idx];
        }
    }
    float fw0 = fcw[j], fw1 = fcw[H + j];
    float bbi = b1_i[j] + b1_h[j];
    float bbg = b1_i[2 * H + j] + b1_h[2 * H + j];
    float bbo = b1_i[3 * H + j] + b1_h[3 * H + j];
    // pin the prefetched registers so the compiler cannot sink the loads
    // past the barrier (round-2 failure mode)
#pragma unroll
    for (int it = 0; it < 8; ++it) {
        asm volatile("" : "+v"(rA[it]), "+v"(rG[it]), "+v"(rO[it]));
    }

    // ---- grid-wide spin barrier (deadlock-free: 256 blocks, all resident)
    __syncthreads();
    if (tid == 0) {
        __threadfence();
        __hip_atomic_fetch_add(&cnt[0], 1u, __ATOMIC_ACQ_REL, __HIP_MEMORY_SCOPE_AGENT);
        while (__hip_atomic_load(&cnt[0], __ATOMIC_ACQUIRE, __HIP_MEMORY_SCOPE_AGENT) != NBLK) {
            __builtin_amdgcn_s_sleep(1);
        }
    }
    __syncthreads();

    // ---- stage fin into LDS via coherence-point (agent atomic) loads
#pragma unroll
    for (int t = 0; t < 8; ++t) {
        int idx = t * 256 + tid;
        finL[idx] = __hip_atomic_load(&fing[idx], __ATOMIC_RELAXED, __HIP_MEMORY_SCOPE_AGENT);
    }
    __syncthreads();

    // ---- phase 2: lstm1 GEMV row j vs register weights, fc fused
    {
        const f32x4* f4 = (const f32x4*)finL;
        float ti = 0.f, tg = 0.f, to = 0.f;
#pragma unroll
        for (int it = 0; it < 8; ++it) {
            int idx = it * 64 + lane;
            f32x4 xv = f4[idx];
            ti += rA[it].x * xv.x + rA[it].y * xv.y + rA[it].z * xv.z + rA[it].w * xv.w;
            tg += rG[it].x * xv.x + rG[it].y * xv.y + rG[it].z * xv.z + rG[it].w * xv.w;
            to += rO[it].x * xv.x + rO[it].y * xv.y + rO[it].z * xv.z + rO[it].w * xv.w;
        }
        ti = wave_sum(ti);
        tg = wave_sum(tg);
        to = wave_sum(to);
        if (lane == 0) {
            float gi = ti + bbi;
            float gg = tg + bbg;
            float go = to + bbo;
            float c = sigmoidf_(gi) * tanhf(gg);
            float h = sigmoidf_(go) * tanhf(c);    // h1[j]
            hs0[wave] = h * fw0;
            hs1[wave] = h * fw1;
        }
    }
    __syncthreads();

    // ---- per-block partial store + last-block fc reduction (no fp atomics)
    if (tid == 0) {
        float p0 = hs0[0] + hs0[1] + hs0[2] + hs0[3];
        float p1 = hs1[0] + hs1[1] + hs1[2] + hs1[3];
        __hip_atomic_store(&pbuf[2 * blockIdx.x],     p0, __ATOMIC_RELAXED, __HIP_MEMORY_SCOPE_AGENT);
        __hip_atomic_store(&pbuf[2 * blockIdx.x + 1], p1, __ATOMIC_RELAXED, __HIP_MEMORY_SCOPE_AGENT);
        unsigned old = __hip_atomic_fetch_add(&cnt[1], 1u, __ATOMIC_ACQ_REL, __HIP_MEMORY_SCOPE_AGENT);
        slast = (old == NBLK - 1) ? 1u : 0u;
    }
    __syncthreads();
    if (slast && wave == 0) {
        float s0 = 0.f, s1 = 0.f;
#pragma unroll
        for (int i = 0; i < 4; ++i) {
            int b = i * 64 + lane;
            s0 += __hip_atomic_load(&pbuf[2 * b],     __ATOMIC_RELAXED, __HIP_MEMORY_SCOPE_AGENT);
            s1 += __hip_atomic_load(&pbuf[2 * b + 1], __ATOMIC_RELAXED, __HIP_MEMORY_SCOPE_AGENT);
        }
        s0 = wave_sum(s0);
        s1 = wave_sum(s1);
        if (lane == 0) {
            out[0] = s0 + fcb[0];
            out[1] = s1 + fcb[1];
        }
    }
}

extern "C" void kernel_launch(void* const* d_in, const int* in_sizes, int n_in,
                              void* d_out, int out_size, void* d_ws, size_t ws_size,
                              hipStream_t stream) {
    const float* goal     = (const float*)d_in[0];
    const float* cur      = (const float*)d_in[1];
    const float* map      = (const float*)d_in[2];
    const float* W_ih_map = (const float*)d_in[3];
    // d_in[4] = W_hh_map  (unused: h0 = 0)
    const float* b_ih_map = (const float*)d_in[5];
    const float* b_hh_map = (const float*)d_in[6];
    const float* W_ih_pts = (const float*)d_in[7];
    // d_in[8] = W_hh_pts  (unused)
    const float* b_ih_pts = (const float*)d_in[9];
    const float* b_hh_pts = (const float*)d_in[10];
    const float* W_ih_1   = (const float*)d_in[11];
    // d_in[12] = W_hh_1   (unused)
    const float* b_ih_1   = (const float*)d_in[13];
    const float* b_hh_1   = (const float*)d_in[14];
    const float* fc_w     = (const float*)d_in[15];
    const float* fc_b     = (const float*)d_in[16];

    unsigned* cnt  = (unsigned*)d_ws;                      // 2 counters
    float*    pbuf = (float*)((char*)d_ws + 64);           // 512 floats
    float*    fing = (float*)((char*)d_ws + 4096);         // 2048 floats
    float*    out  = (float*)d_out;

    // zero the barrier/tail counters every call (graph memset node)
    hipMemsetAsync(d_ws, 0, 8, stream);

    k_all<<<NBLK, 256, 0, stream>>>(map, W_ih_map, b_ih_map, b_hh_map,
                                    W_ih_pts, b_ih_pts, b_hh_pts,
                                    W_ih_1, b_ih_1, b_hh_1,
                                    goal, cur, fc_w, fc_b,
                                    cnt, pbuf, fing, out);
}

// Round 5
// 46.525 us; speedup vs baseline: 1.1663x; 1.1663x over previous
//
#include <hip/hip_runtime.h>
#include <math.h>

#define H  1024
#define D2 2048      // input width of both big GEMVs
#define NPROD 256    // producer blocks (map cell)
#define NCONS 256    // consumer blocks (lstm1 + fc)

typedef float f32x4 __attribute__((ext_vector_type(4)));

__device__ __forceinline__ float sigmoidf_(float x) {
    return 1.0f / (1.0f + expf(-x));
}

__device__ __forceinline__ float wave_sum(float v) {
#pragma unroll
    for (int off = 32; off >= 1; off >>= 1)
        v += __shfl_xor(v, off, 64);
    return v;
}

// 512 blocks x 256 threads, 2 blocks/CU (launch_bounds caps VGPR<=256, grid ==
// residency capacity -> all blocks co-resident; producers never wait, so no
// deadlock). Blocks 0..255: map cell -> fin. Blocks 256..511: prefetch W_ih_1
// rows into registers (overlapping the producers' streaming), relaxed-spin on
// a ticket counter (no per-iteration cache maintenance), then lstm1 + fused fc.
// ws layout: [0..7] counters (zeroed per call by memset node),
// [64..2111] pbuf (512 floats), [4096..12287] fin (2048 floats).
__global__ __launch_bounds__(256, 2) void k_all(
    const float* __restrict__ x,      // map [2048]
    const float* __restrict__ Wm,     // W_ih_map [4096][2048]
    const float* __restrict__ bm_i,
    const float* __restrict__ bm_h,
    const float* __restrict__ Wp,     // W_ih_pts [4096][4]
    const float* __restrict__ bp_i,
    const float* __restrict__ bp_h,
    const float* __restrict__ W1,     // W_ih_1 [4096][2048]
    const float* __restrict__ b1_i,
    const float* __restrict__ b1_h,
    const float* __restrict__ goal,   // [2]
    const float* __restrict__ cur,    // [2]
    const float* __restrict__ fcw,    // [2][1024]
    const float* __restrict__ fcb,    // [2]
    unsigned*    __restrict__ cnt,    // ws: [0]=fin-ready, [1]=fc ticket
    float*       __restrict__ pbuf,   // ws: 512 floats (per-block fc partials)
    float*       __restrict__ fing,   // ws: 2048 floats (final_in)
    float*       __restrict__ out)    // [2]
{
    const int tid  = threadIdx.x;
    const int wave = tid >> 6;
    const int lane = tid & 63;

    if (blockIdx.x < NPROD) {
        // ================= PRODUCER: map cell + points cell =================
        const int j = blockIdx.x * 4 + wave;

        if (lane == 0) {   // trivial points cell for this wave's j
            float p0 = cur[0], p1 = cur[1], p2 = goal[0], p3 = goal[1];
            const f32x4* Wp4 = (const f32x4*)Wp;   // one f32x4 per row
            f32x4 wi = Wp4[j];
            f32x4 wg = Wp4[2 * H + j];
            f32x4 wo = Wp4[3 * H + j];
            float gi = wi.x * p0 + wi.y * p1 + wi.z * p2 + wi.w * p3 + bp_i[j] + bp_h[j];
            float gg = wg.x * p0 + wg.y * p1 + wg.z * p2 + wg.w * p3 + bp_i[2 * H + j] + bp_h[2 * H + j];
            float go = wo.x * p0 + wo.y * p1 + wo.z * p2 + wo.w * p3 + bp_i[3 * H + j] + bp_h[3 * H + j];
            float c = sigmoidf_(gi) * tanhf(gg);
            fing[H + j] = sigmoidf_(go) * tanhf(c);
        }

        // full-K GEMV row j of the map cell (gates i, g, o)
        const f32x4* x4 = (const f32x4*)x;
        const f32x4* Wi = (const f32x4*)(Wm + (size_t)j * D2);
        const f32x4* Wg = (const f32x4*)(Wm + (size_t)(2 * H + j) * D2);
        const f32x4* Wo = (const f32x4*)(Wm + (size_t)(3 * H + j) * D2);
        float si = 0.f, sg = 0.f, so = 0.f;
#pragma unroll
        for (int it = 0; it < 8; ++it) {
            int idx = it * 64 + lane;          // 512 f32x4 per row
            f32x4 xv = x4[idx];
            f32x4 a = Wi[idx];
            si += a.x * xv.x + a.y * xv.y + a.z * xv.z + a.w * xv.w;
            f32x4 g = Wg[idx];
            sg += g.x * xv.x + g.y * xv.y + g.z * xv.z + g.w * xv.w;
            f32x4 o = Wo[idx];
            so += o.x * xv.x + o.y * xv.y + o.z * xv.z + o.w * xv.w;
        }
        si = wave_sum(si);
        sg = wave_sum(sg);
        so = wave_sum(so);
        if (lane == 0) {
            float gi = si + bm_i[j] + bm_h[j];
            float gg = sg + bm_i[2 * H + j] + bm_h[2 * H + j];
            float go = so + bm_i[3 * H + j] + bm_h[3 * H + j];
            float c = sigmoidf_(gi) * tanhf(gg);
            fing[j] = sigmoidf_(go) * tanhf(c);    // h_map[j]
        }
        __syncthreads();
        if (tid == 0) {
            __threadfence();   // release: make fin stores visible (L2 wb)
            __hip_atomic_fetch_add(&cnt[0], 1u, __ATOMIC_RELAXED, __HIP_MEMORY_SCOPE_AGENT);
        }
        return;
    }

    // =================== CONSUMER: lstm1 + fused fc =======================
    const int bc = blockIdx.x - NPROD;
    const int j  = bc * 4 + wave;

    __shared__ float    finL[2048];
    __shared__ float    hs0[4], hs1[4];
    __shared__ unsigned slast;

    // prefetch W_ih_1 rows for j into registers — streams concurrently with
    // the producers' W_ih_map streaming; does not depend on fin
    f32x4 rA[8], rG[8], rO[8];
    {
        const f32x4* Vi = (const f32x4*)(W1 + (size_t)j * D2);
        const f32x4* Vg = (const f32x4*)(W1 + (size_t)(2 * H + j) * D2);
        const f32x4* Vo = (const f32x4*)(W1 + (size_t)(3 * H + j) * D2);
#pragma unroll
        for (int it = 0; it < 8; ++it) {
            int idx = it * 64 + lane;
            rA[it] = Vi[idx];
            rG[it] = Vg[idx];
            rO[it] = Vo[idx];
        }
    }
    float fw0 = fcw[j], fw1 = fcw[H + j];
    float bbi = b1_i[j] + b1_h[j];
    float bbg = b1_i[2 * H + j] + b1_h[2 * H + j];
    float bbo = b1_i[3 * H + j] + b1_h[3 * H + j];
    // pin: loads must complete here, not get sunk past the spin
#pragma unroll
    for (int it = 0; it < 8; ++it) {
        asm volatile("" : "+v"(rA[it]), "+v"(rG[it]), "+v"(rO[it]));
    }

    // relaxed spin (no cache maintenance per iteration), one acquire after
    if (tid == 0) {
        while (__hip_atomic_load(&cnt[0], __ATOMIC_RELAXED, __HIP_MEMORY_SCOPE_AGENT) != NPROD) {
            __builtin_amdgcn_s_sleep(8);
        }
        __threadfence();   // acquire: invalidate stale L1/L2 before fin reads
    }
    __syncthreads();

    // stage fin into LDS (plain vectorized loads; fence above made them fresh)
    {
        const f32x4* fg4 = (const f32x4*)fing;
        f32x4 v0 = fg4[tid];               // 256 threads x 16B = 4KB
        f32x4 v1 = fg4[256 + tid];         // second 4KB
        ((f32x4*)finL)[tid]       = v0;
        ((f32x4*)finL)[256 + tid] = v1;
    }
    __syncthreads();

    // lstm1 GEMV row j vs register-resident weights
    {
        const f32x4* f4 = (const f32x4*)finL;
        float ti = 0.f, tg = 0.f, to = 0.f;
#pragma unroll
        for (int it = 0; it < 8; ++it) {
            int idx = it * 64 + lane;
            f32x4 xv = f4[idx];
            ti += rA[it].x * xv.x + rA[it].y * xv.y + rA[it].z * xv.z + rA[it].w * xv.w;
            tg += rG[it].x * xv.x + rG[it].y * xv.y + rG[it].z * xv.z + rG[it].w * xv.w;
            to += rO[it].x * xv.x + rO[it].y * xv.y + rO[it].z * xv.z + rO[it].w * xv.w;
        }
        ti = wave_sum(ti);
        tg = wave_sum(tg);
        to = wave_sum(to);
        if (lane == 0) {
            float gi = ti + bbi;
            float gg = tg + bbg;
            float go = to + bbo;
            float c = sigmoidf_(gi) * tanhf(gg);
            float h = sigmoidf_(go) * tanhf(c);    // h1[j]
            hs0[wave] = h * fw0;
            hs1[wave] = h * fw1;
        }
    }
    __syncthreads();

    // per-block fc partials -> pbuf, int ticket, last block reduces
    if (tid == 0) {
        pbuf[2 * bc]     = hs0[0] + hs0[1] + hs0[2] + hs0[3];
        pbuf[2 * bc + 1] = hs1[0] + hs1[1] + hs1[2] + hs1[3];
        __threadfence();   // release partials
        unsigned old = __hip_atomic_fetch_add(&cnt[1], 1u, __ATOMIC_RELAXED, __HIP_MEMORY_SCOPE_AGENT);
        slast = (old == NCONS - 1) ? 1u : 0u;
    }
    __syncthreads();
    if (slast && wave == 0) {
        if (lane == 0) __threadfence();    // acquire other blocks' partials
        __builtin_amdgcn_wave_barrier();
        float s0 = 0.f, s1 = 0.f;
#pragma unroll
        for (int i = 0; i < 4; ++i) {
            int b = i * 64 + lane;
            s0 += pbuf[2 * b];
            s1 += pbuf[2 * b + 1];
        }
        s0 = wave_sum(s0);
        s1 = wave_sum(s1);
        if (lane == 0) {
            out[0] = s0 + fcb[0];
            out[1] = s1 + fcb[1];
        }
    }
}

extern "C" void kernel_launch(void* const* d_in, const int* in_sizes, int n_in,
                              void* d_out, int out_size, void* d_ws, size_t ws_size,
                              hipStream_t stream) {
    const float* goal     = (const float*)d_in[0];
    const float* cur      = (const float*)d_in[1];
    const float* map      = (const float*)d_in[2];
    const float* W_ih_map = (const float*)d_in[3];
    // d_in[4] = W_hh_map  (unused: h0 = 0)
    const float* b_ih_map = (const float*)d_in[5];
    const float* b_hh_map = (const float*)d_in[6];
    const float* W_ih_pts = (const float*)d_in[7];
    // d_in[8] = W_hh_pts  (unused)
    const float* b_ih_pts = (const float*)d_in[9];
    const float* b_hh_pts = (const float*)d_in[10];
    const float* W_ih_1   = (const float*)d_in[11];
    // d_in[12] = W_hh_1   (unused)
    const float* b_ih_1   = (const float*)d_in[13];
    const float* b_hh_1   = (const float*)d_in[14];
    const float* fc_w     = (const float*)d_in[15];
    const float* fc_b     = (const float*)d_in[16];

    unsigned* cnt  = (unsigned*)d_ws;                      // 2 counters
    float*    pbuf = (float*)((char*)d_ws + 64);           // 512 floats
    float*    fing = (float*)((char*)d_ws + 4096);         // 2048 floats
    float*    out  = (float*)d_out;

    // zero both counters every call (graph memset node, proven in round 4)
    hipMemsetAsync(d_ws, 0, 8, stream);

    k_all<<<NPROD + NCONS, 256, 0, stream>>>(
        map, W_ih_map, b_ih_map, b_hh_map,
        W_ih_pts, b_ih_pts, b_hh_pts,
        W_ih_1, b_ih_1, b_hh_1,
        goal, cur, fc_w, fc_b,
        cnt, pbuf, fing, out);
}

// Round 6
// 27.239 us; speedup vs baseline: 1.9921x; 1.7080x over previous
//
#include <hip/hip_runtime.h>
#include <math.h>

#define H    1024
#define D2   2048    // input width of both big GEMVs
#define NB2  256     // blocks in kernel 2

typedef float f32x4 __attribute__((ext_vector_type(4)));

__device__ __forceinline__ float sigmoidf_(float x) {
    return 1.0f / (1.0f + expf(-x));
}

__device__ __forceinline__ float wave_sum(float v) {
#pragma unroll
    for (int off = 32; off >= 1; off >>= 1)
        v += __shfl_xor(v, off, 64);
    return v;
}

// Kernel 1 (proven round-1 structure): blocks 0..255 compute h_map (one wave
// per hidden j, rows i/g/o full-K). Block 256 computes h_pts.
// Writes final_in = [h_map | h_pts] into ws.
__global__ __launch_bounds__(256) void k_first(
    const float* __restrict__ x,       // map [2048]
    const float* __restrict__ W,       // W_ih_map [4096][2048]
    const float* __restrict__ b_ih,
    const float* __restrict__ b_hh,
    const float* __restrict__ Wp,      // W_ih_pts [4096][4]
    const float* __restrict__ bp_ih,
    const float* __restrict__ bp_hh,
    const float* __restrict__ goal,
    const float* __restrict__ cur,
    float* __restrict__ fin)           // ws: [0..1023]=h_map, [1024..2047]=h_pts
{
    int b = blockIdx.x;
    if (b < 256) {
        int wave = threadIdx.x >> 6;
        int lane = threadIdx.x & 63;
        int j = b * 4 + wave;
        const f32x4* x4 = (const f32x4*)x;
        const f32x4* Wi = (const f32x4*)(W + (size_t)j * D2);
        const f32x4* Wg = (const f32x4*)(W + (size_t)(2 * H + j) * D2);
        const f32x4* Wo = (const f32x4*)(W + (size_t)(3 * H + j) * D2);
        float si = 0.f, sg = 0.f, so = 0.f;
#pragma unroll
        for (int it = 0; it < 8; ++it) {
            int idx = it * 64 + lane;   // 512 f32x4 per row
            f32x4 xv = x4[idx];
            f32x4 a = Wi[idx];
            si += a.x * xv.x + a.y * xv.y + a.z * xv.z + a.w * xv.w;
            f32x4 g = Wg[idx];
            sg += g.x * xv.x + g.y * xv.y + g.z * xv.z + g.w * xv.w;
            f32x4 o = Wo[idx];
            so += o.x * xv.x + o.y * xv.y + o.z * xv.z + o.w * xv.w;
        }
        si = wave_sum(si);
        sg = wave_sum(sg);
        so = wave_sum(so);
        if (lane == 0) {
            float gi = si + b_ih[j] + b_hh[j];
            float gg = sg + b_ih[2 * H + j] + b_hh[2 * H + j];
            float go = so + b_ih[3 * H + j] + b_hh[3 * H + j];
            float c = sigmoidf_(gi) * tanhf(gg);
            fin[j] = sigmoidf_(go) * tanhf(c);    // h_map[j]
        }
    } else {
        // points cell: points = [cur0, cur1, goal0, goal1]
        float p0 = cur[0], p1 = cur[1], p2 = goal[0], p3 = goal[1];
        const f32x4* Wp4 = (const f32x4*)Wp;     // one f32x4 per row
#pragma unroll
        for (int t = 0; t < 4; ++t) {
            int j = t * 256 + threadIdx.x;
            f32x4 wi = Wp4[j];
            f32x4 wg = Wp4[2 * H + j];
            f32x4 wo = Wp4[3 * H + j];
            float gi = wi.x * p0 + wi.y * p1 + wi.z * p2 + wi.w * p3 + bp_ih[j] + bp_hh[j];
            float gg = wg.x * p0 + wg.y * p1 + wg.z * p2 + wg.w * p3 + bp_ih[2 * H + j] + bp_hh[2 * H + j];
            float go = wo.x * p0 + wo.y * p1 + wo.z * p2 + wo.w * p3 + bp_ih[3 * H + j] + bp_hh[3 * H + j];
            float c = sigmoidf_(gi) * tanhf(gg);
            fin[H + j] = sigmoidf_(go) * tanhf(c);  // h_pts[j]
        }
    }
}

// Kernel 2: lstm1 cell (one wave per j, full-K) + FUSED fc via ticket tail:
// per-block partials -> agent atomic stores, int ticket, last block reduces
// 512 floats and writes out. No fp atomics, no spin.
__global__ __launch_bounds__(256) void k_l1fc(
    const float* __restrict__ fin,     // ws [2048]
    const float* __restrict__ W1,      // W_ih_1 [4096][2048]
    const float* __restrict__ b1_i,
    const float* __restrict__ b1_h,
    const float* __restrict__ fcw,     // [2][1024]
    const float* __restrict__ fcb,     // [2]
    unsigned*    __restrict__ cnt,     // ws: ticket (zeroed per call)
    float*       __restrict__ pbuf,    // ws: 512 floats
    float* __restrict__ out)           // [2]
{
    const int tid  = threadIdx.x;
    const int wave = tid >> 6;
    const int lane = tid & 63;
    const int j    = blockIdx.x * 4 + wave;

    __shared__ float    hs0[4], hs1[4];
    __shared__ unsigned slast;

    {
        const f32x4* f4 = (const f32x4*)fin;
        const f32x4* Wi = (const f32x4*)(W1 + (size_t)j * D2);
        const f32x4* Wg = (const f32x4*)(W1 + (size_t)(2 * H + j) * D2);
        const f32x4* Wo = (const f32x4*)(W1 + (size_t)(3 * H + j) * D2);
        float si = 0.f, sg = 0.f, so = 0.f;
#pragma unroll
        for (int it = 0; it < 8; ++it) {
            int idx = it * 64 + lane;
            f32x4 xv = f4[idx];
            f32x4 a = Wi[idx];
            si += a.x * xv.x + a.y * xv.y + a.z * xv.z + a.w * xv.w;
            f32x4 g = Wg[idx];
            sg += g.x * xv.x + g.y * xv.y + g.z * xv.z + g.w * xv.w;
            f32x4 o = Wo[idx];
            so += o.x * xv.x + o.y * xv.y + o.z * xv.z + o.w * xv.w;
        }
        si = wave_sum(si);
        sg = wave_sum(sg);
        so = wave_sum(so);
        if (lane == 0) {
            float gi = si + b1_i[j] + b1_h[j];
            float gg = sg + b1_i[2 * H + j] + b1_h[2 * H + j];
            float go = so + b1_i[3 * H + j] + b1_h[3 * H + j];
            float c = sigmoidf_(gi) * tanhf(gg);
            float h = sigmoidf_(go) * tanhf(c);     // h1[j]
            hs0[wave] = h * fcw[j];
            hs1[wave] = h * fcw[H + j];
        }
    }
    __syncthreads();

    if (tid == 0) {
        float p0 = hs0[0] + hs0[1] + hs0[2] + hs0[3];
        float p1 = hs1[0] + hs1[1] + hs1[2] + hs1[3];
        __hip_atomic_store(&pbuf[2 * blockIdx.x],     p0, __ATOMIC_RELAXED, __HIP_MEMORY_SCOPE_AGENT);
        __hip_atomic_store(&pbuf[2 * blockIdx.x + 1], p1, __ATOMIC_RELAXED, __HIP_MEMORY_SCOPE_AGENT);
        unsigned old = __hip_atomic_fetch_add(&cnt[0], 1u, __ATOMIC_ACQ_REL, __HIP_MEMORY_SCOPE_AGENT);
        slast = (old == NB2 - 1) ? 1u : 0u;
    }
    __syncthreads();

    if (slast && wave == 0) {
        float s0 = 0.f, s1 = 0.f;
#pragma unroll
        for (int i = 0; i < 4; ++i) {
            int b = i * 64 + lane;
            s0 += __hip_atomic_load(&pbuf[2 * b],     __ATOMIC_RELAXED, __HIP_MEMORY_SCOPE_AGENT);
            s1 += __hip_atomic_load(&pbuf[2 * b + 1], __ATOMIC_RELAXED, __HIP_MEMORY_SCOPE_AGENT);
        }
        s0 = wave_sum(s0);
        s1 = wave_sum(s1);
        if (lane == 0) {
            out[0] = s0 + fcb[0];
            out[1] = s1 + fcb[1];
        }
    }
}

extern "C" void kernel_launch(void* const* d_in, const int* in_sizes, int n_in,
                              void* d_out, int out_size, void* d_ws, size_t ws_size,
                              hipStream_t stream) {
    const float* goal     = (const float*)d_in[0];
    const float* cur      = (const float*)d_in[1];
    const float* map      = (const float*)d_in[2];
    const float* W_ih_map = (const float*)d_in[3];
    // d_in[4] = W_hh_map  (unused: h0 = 0)
    const float* b_ih_map = (const float*)d_in[5];
    const float* b_hh_map = (const float*)d_in[6];
    const float* W_ih_pts = (const float*)d_in[7];
    // d_in[8] = W_hh_pts  (unused)
    const float* b_ih_pts = (const float*)d_in[9];
    const float* b_hh_pts = (const float*)d_in[10];
    const float* W_ih_1   = (const float*)d_in[11];
    // d_in[12] = W_hh_1   (unused)
    const float* b_ih_1   = (const float*)d_in[13];
    const float* b_hh_1   = (const float*)d_in[14];
    const float* fc_w     = (const float*)d_in[15];
    const float* fc_b     = (const float*)d_in[16];

    unsigned* cnt  = (unsigned*)d_ws;                  // ticket
    float*    pbuf = (float*)((char*)d_ws + 64);       // 512 floats
    float*    fin  = (float*)((char*)d_ws + 4096);     // 2048 floats
    float*    out  = (float*)d_out;

    hipMemsetAsync(d_ws, 0, 8, stream);   // zero the ticket each call

    k_first<<<257, 256, 0, stream>>>(map, W_ih_map, b_ih_map, b_hh_map,
                                     W_ih_pts, b_ih_pts, b_hh_pts,
                                     goal, cur, fin);
    k_l1fc<<<NB2, 256, 0, stream>>>(fin, W_ih_1, b_ih_1, b_hh_1,
                                    fc_w, fc_b, cnt, pbuf, out);
}

// Round 7
// 22.033 us; speedup vs baseline: 2.4628x; 1.2363x over previous
//
#include <hip/hip_runtime.h>
#include <math.h>

#define H    1024
#define D2   2048    // input width of both big GEMVs
#define NB2  256     // blocks in kernel 2

typedef float f32x4 __attribute__((ext_vector_type(4)));

__device__ __forceinline__ float sigmoidf_(float x) {
    return 1.0f / (1.0f + expf(-x));
}

__device__ __forceinline__ float wave_sum(float v) {
#pragma unroll
    for (int off = 32; off >= 1; off >>= 1)
        v += __shfl_xor(v, off, 64);
    return v;
}

// Kernel 1: blocks 0..255 compute h_map (one wave per hidden j, gate rows
// i/g/o, full-K). Block 256 computes h_pts AND zeroes the fc ticket counter
// (visible to kernel 2 via the kernel-boundary release — no memset node).
__global__ __launch_bounds__(256) void k_first(
    const float* __restrict__ x,       // map [2048]
    const float* __restrict__ W,       // W_ih_map [4096][2048]
    const float* __restrict__ b_ih,
    const float* __restrict__ b_hh,
    const float* __restrict__ Wp,      // W_ih_pts [4096][4]
    const float* __restrict__ bp_ih,
    const float* __restrict__ bp_hh,
    const float* __restrict__ goal,
    const float* __restrict__ cur,
    unsigned*    __restrict__ cnt,     // ws ticket (zeroed here each call)
    float* __restrict__ fin)           // ws: [0..1023]=h_map, [1024..2047]=h_pts
{
    int b = blockIdx.x;
    if (b < 256) {
        int wave = threadIdx.x >> 6;
        int lane = threadIdx.x & 63;
        int j = b * 4 + wave;
        const f32x4* x4 = (const f32x4*)x;
        const f32x4* Wi = (const f32x4*)(W + (size_t)j * D2);
        const f32x4* Wg = (const f32x4*)(W + (size_t)(2 * H + j) * D2);
        const f32x4* Wo = (const f32x4*)(W + (size_t)(3 * H + j) * D2);
        float si = 0.f, sg = 0.f, so = 0.f;
#pragma unroll
        for (int it = 0; it < 8; ++it) {
            int idx = it * 64 + lane;   // 512 f32x4 per row
            f32x4 xv = x4[idx];
            f32x4 a = Wi[idx];
            si += a.x * xv.x + a.y * xv.y + a.z * xv.z + a.w * xv.w;
            f32x4 g = Wg[idx];
            sg += g.x * xv.x + g.y * xv.y + g.z * xv.z + g.w * xv.w;
            f32x4 o = Wo[idx];
            so += o.x * xv.x + o.y * xv.y + o.z * xv.z + o.w * xv.w;
        }
        si = wave_sum(si);
        sg = wave_sum(sg);
        so = wave_sum(so);
        if (lane == 0) {
            float gi = si + b_ih[j] + b_hh[j];
            float gg = sg + b_ih[2 * H + j] + b_hh[2 * H + j];
            float go = so + b_ih[3 * H + j] + b_hh[3 * H + j];
            float c = sigmoidf_(gi) * tanhf(gg);
            fin[j] = sigmoidf_(go) * tanhf(c);    // h_map[j]
        }
    } else {
        // zero the fc ticket for kernel 2 (once per call, no extra node)
        if (threadIdx.x == 0) {
            __hip_atomic_store(&cnt[0], 0u, __ATOMIC_RELAXED, __HIP_MEMORY_SCOPE_AGENT);
        }
        // points cell: points = [cur0, cur1, goal0, goal1]
        float p0 = cur[0], p1 = cur[1], p2 = goal[0], p3 = goal[1];
        const f32x4* Wp4 = (const f32x4*)Wp;     // one f32x4 per row
#pragma unroll
        for (int t = 0; t < 4; ++t) {
            int j = t * 256 + threadIdx.x;
            f32x4 wi = Wp4[j];
            f32x4 wg = Wp4[2 * H + j];
            f32x4 wo = Wp4[3 * H + j];
            float gi = wi.x * p0 + wi.y * p1 + wi.z * p2 + wi.w * p3 + bp_ih[j] + bp_hh[j];
            float gg = wg.x * p0 + wg.y * p1 + wg.z * p2 + wg.w * p3 + bp_ih[2 * H + j] + bp_hh[2 * H + j];
            float go = wo.x * p0 + wo.y * p1 + wo.z * p2 + wo.w * p3 + bp_ih[3 * H + j] + bp_hh[3 * H + j];
            float c = sigmoidf_(gi) * tanhf(gg);
            fin[H + j] = sigmoidf_(go) * tanhf(c);  // h_pts[j]
        }
    }
}

// Kernel 2: lstm1 cell (one wave per j, full-K) + fused fc tail:
// per-block partials via agent-scope stores, RELEASE fetch_add ticket
// (no acq_rel invalidate storm), last block fences once and reduces.
__global__ __launch_bounds__(256) void k_l1fc(
    const float* __restrict__ fin,     // ws [2048]
    const float* __restrict__ W1,      // W_ih_1 [4096][2048]
    const float* __restrict__ b1_i,
    const float* __restrict__ b1_h,
    const float* __restrict__ fcw,     // [2][1024]
    const float* __restrict__ fcb,     // [2]
    unsigned*    __restrict__ cnt,     // ws ticket (zeroed by k_first)
    float*       __restrict__ pbuf,    // ws: 512 floats
    float* __restrict__ out)           // [2]
{
    const int tid  = threadIdx.x;
    const int wave = tid >> 6;
    const int lane = tid & 63;
    const int j    = blockIdx.x * 4 + wave;

    __shared__ float    hs0[4], hs1[4];
    __shared__ unsigned slast;

    {
        const f32x4* f4 = (const f32x4*)fin;
        const f32x4* Wi = (const f32x4*)(W1 + (size_t)j * D2);
        const f32x4* Wg = (const f32x4*)(W1 + (size_t)(2 * H + j) * D2);
        const f32x4* Wo = (const f32x4*)(W1 + (size_t)(3 * H + j) * D2);
        float si = 0.f, sg = 0.f, so = 0.f;
#pragma unroll
        for (int it = 0; it < 8; ++it) {
            int idx = it * 64 + lane;
            f32x4 xv = f4[idx];
            f32x4 a = Wi[idx];
            si += a.x * xv.x + a.y * xv.y + a.z * xv.z + a.w * xv.w;
            f32x4 g = Wg[idx];
            sg += g.x * xv.x + g.y * xv.y + g.z * xv.z + g.w * xv.w;
            f32x4 o = Wo[idx];
            so += o.x * xv.x + o.y * xv.y + o.z * xv.z + o.w * xv.w;
        }
        si = wave_sum(si);
        sg = wave_sum(sg);
        so = wave_sum(so);
        if (lane == 0) {
            float gi = si + b1_i[j] + b1_h[j];
            float gg = sg + b1_i[2 * H + j] + b1_h[2 * H + j];
            float go = so + b1_i[3 * H + j] + b1_h[3 * H + j];
            float c = sigmoidf_(gi) * tanhf(gg);
            float h = sigmoidf_(go) * tanhf(c);     // h1[j]
            hs0[wave] = h * fcw[j];
            hs1[wave] = h * fcw[H + j];
        }
    }
    __syncthreads();

    if (tid == 0) {
        float p0 = hs0[0] + hs0[1] + hs0[2] + hs0[3];
        float p1 = hs1[0] + hs1[1] + hs1[2] + hs1[3];
        __hip_atomic_store(&pbuf[2 * blockIdx.x],     p0, __ATOMIC_RELAXED, __HIP_MEMORY_SCOPE_AGENT);
        __hip_atomic_store(&pbuf[2 * blockIdx.x + 1], p1, __ATOMIC_RELAXED, __HIP_MEMORY_SCOPE_AGENT);
        unsigned old = __hip_atomic_fetch_add(&cnt[0], 1u, __ATOMIC_RELEASE, __HIP_MEMORY_SCOPE_AGENT);
        slast = (old == NB2 - 1) ? 1u : 0u;
    }
    __syncthreads();

    if (slast && wave == 0) {
        __threadfence();   // one acquire-side fence in the single winner wave
        float s0 = 0.f, s1 = 0.f;
#pragma unroll
        for (int i = 0; i < 4; ++i) {
            int b = i * 64 + lane;
            s0 += __hip_atomic_load(&pbuf[2 * b],     __ATOMIC_RELAXED, __HIP_MEMORY_SCOPE_AGENT);
            s1 += __hip_atomic_load(&pbuf[2 * b + 1], __ATOMIC_RELAXED, __HIP_MEMORY_SCOPE_AGENT);
        }
        s0 = wave_sum(s0);
        s1 = wave_sum(s1);
        if (lane == 0) {
            out[0] = s0 + fcb[0];
            out[1] = s1 + fcb[1];
        }
    }
}

extern "C" void kernel_launch(void* const* d_in, const int* in_sizes, int n_in,
                              void* d_out, int out_size, void* d_ws, size_t ws_size,
                              hipStream_t stream) {
    const float* goal     = (const float*)d_in[0];
    const float* cur      = (const float*)d_in[1];
    const float* map      = (const float*)d_in[2];
    const float* W_ih_map = (const float*)d_in[3];
    // d_in[4] = W_hh_map  (unused: h0 = 0)
    const float* b_ih_map = (const float*)d_in[5];
    const float* b_hh_map = (const float*)d_in[6];
    const float* W_ih_pts = (const float*)d_in[7];
    // d_in[8] = W_hh_pts  (unused)
    const float* b_ih_pts = (const float*)d_in[9];
    const float* b_hh_pts = (const float*)d_in[10];
    const float* W_ih_1   = (const float*)d_in[11];
    // d_in[12] = W_hh_1   (unused)
    const float* b_ih_1   = (const float*)d_in[13];
    const float* b_hh_1   = (const float*)d_in[14];
    const float* fc_w     = (const float*)d_in[15];
    const float* fc_b     = (const float*)d_in[16];

    unsigned* cnt  = (unsigned*)d_ws;                  // ticket
    float*    pbuf = (float*)((char*)d_ws + 64);       // 512 floats
    float*    fin  = (float*)((char*)d_ws + 4096);     // 2048 floats
    float*    out  = (float*)d_out;

    k_first<<<257, 256, 0, stream>>>(map, W_ih_map, b_ih_map, b_hh_map,
                                     W_ih_pts, b_ih_pts, b_hh_pts,
                                     goal, cur, cnt, fin);
    k_l1fc<<<NB2, 256, 0, stream>>>(fin, W_ih_1, b_ih_1, b_hh_1,
                                    fc_w, fc_b, cnt, pbuf, out);
}

// Round 8
// 18.992 us; speedup vs baseline: 2.8573x; 1.1601x over previous
//
#include <hip/hip_runtime.h>
#include <math.h>

#define H    1024
#define D2   2048    // input width of both big GEMVs

typedef float f32x4 __attribute__((ext_vector_type(4)));

__device__ __forceinline__ float sigmoidf_(float x) {
    return 1.0f / (1.0f + expf(-x));
}

__device__ __forceinline__ float wave_sum(float v) {
#pragma unroll
    for (int off = 32; off >= 1; off >>= 1)
        v += __shfl_xor(v, off, 64);
    return v;
}

// Deep-prefetch GEMV core: load the wave's whole 3-row tile (24 f32x4 = 96
// VGPRs) + x (8 f32x4) as one straight-line burst, then FMA. 4 waves/CU x
// 24KB in flight = 96KB/CU >> Little's-law need (~22KB) -> HBM-saturating.
// __launch_bounds__(256,1) lifts the VGPR cap to 256 so nothing spills.
__device__ __forceinline__ void gemv3_deep(
    const f32x4* __restrict__ x4,   // 512 f32x4 (shared input vector)
    const f32x4* __restrict__ Wi,
    const f32x4* __restrict__ Wg,
    const f32x4* __restrict__ Wo,
    int lane, float& si, float& sg, float& so)
{
    f32x4 xv[8], wa[8], wg[8], wo[8];
#pragma unroll
    for (int it = 0; it < 8; ++it) xv[it] = x4[it * 64 + lane];
#pragma unroll
    for (int it = 0; it < 8; ++it) wa[it] = Wi[it * 64 + lane];
#pragma unroll
    for (int it = 0; it < 8; ++it) wg[it] = Wg[it * 64 + lane];
#pragma unroll
    for (int it = 0; it < 8; ++it) wo[it] = Wo[it * 64 + lane];

    float a = 0.f, b = 0.f, c = 0.f;
#pragma unroll
    for (int it = 0; it < 8; ++it) {
        a += wa[it].x * xv[it].x + wa[it].y * xv[it].y + wa[it].z * xv[it].z + wa[it].w * xv[it].w;
        b += wg[it].x * xv[it].x + wg[it].y * xv[it].y + wg[it].z * xv[it].z + wg[it].w * xv[it].w;
        c += wo[it].x * xv[it].x + wo[it].y * xv[it].y + wo[it].z * xv[it].z + wo[it].w * xv[it].w;
    }
    si = wave_sum(a);
    sg = wave_sum(b);
    so = wave_sum(c);
}

// Kernel 1: blocks 0..255 -> h_map (one wave per hidden j); block 256 -> h_pts.
__global__ __launch_bounds__(256, 1) void k_first(
    const float* __restrict__ x,       // map [2048]
    const float* __restrict__ W,       // W_ih_map [4096][2048]
    const float* __restrict__ b_ih,
    const float* __restrict__ b_hh,
    const float* __restrict__ Wp,      // W_ih_pts [4096][4]
    const float* __restrict__ bp_ih,
    const float* __restrict__ bp_hh,
    const float* __restrict__ goal,
    const float* __restrict__ cur,
    float* __restrict__ fin)           // ws: [0..1023]=h_map, [1024..2047]=h_pts
{
    int b = blockIdx.x;
    if (b < 256) {
        int wave = threadIdx.x >> 6;
        int lane = threadIdx.x & 63;
        int j = b * 4 + wave;
        float si, sg, so;
        gemv3_deep((const f32x4*)x,
                   (const f32x4*)(W + (size_t)j * D2),
                   (const f32x4*)(W + (size_t)(2 * H + j) * D2),
                   (const f32x4*)(W + (size_t)(3 * H + j) * D2),
                   lane, si, sg, so);
        if (lane == 0) {
            float gi = si + b_ih[j] + b_hh[j];
            float gg = sg + b_ih[2 * H + j] + b_hh[2 * H + j];
            float go = so + b_ih[3 * H + j] + b_hh[3 * H + j];
            float c = sigmoidf_(gi) * tanhf(gg);
            fin[j] = sigmoidf_(go) * tanhf(c);    // h_map[j]
        }
    } else {
        // points cell: points = [cur0, cur1, goal0, goal1]
        float p0 = cur[0], p1 = cur[1], p2 = goal[0], p3 = goal[1];
        const f32x4* Wp4 = (const f32x4*)Wp;     // one f32x4 per row
#pragma unroll
        for (int t = 0; t < 4; ++t) {
            int j = t * 256 + threadIdx.x;
            f32x4 wi = Wp4[j];
            f32x4 wg = Wp4[2 * H + j];
            f32x4 wo = Wp4[3 * H + j];
            float gi = wi.x * p0 + wi.y * p1 + wi.z * p2 + wi.w * p3 + bp_ih[j] + bp_hh[j];
            float gg = wg.x * p0 + wg.y * p1 + wg.z * p2 + wg.w * p3 + bp_ih[2 * H + j] + bp_hh[2 * H + j];
            float go = wo.x * p0 + wo.y * p1 + wo.z * p2 + wo.w * p3 + bp_ih[3 * H + j] + bp_hh[3 * H + j];
            float c = sigmoidf_(gi) * tanhf(gg);
            fin[H + j] = sigmoidf_(go) * tanhf(c);  // h_pts[j]
        }
    }
}

// Kernel 2: lstm1 cell on fin -> h1 (same deep-prefetch GEMV)
__global__ __launch_bounds__(256, 1) void k_lstm1(
    const float* __restrict__ fin,     // ws [2048]
    const float* __restrict__ W1,      // W_ih_1 [4096][2048]
    const float* __restrict__ b1_i,
    const float* __restrict__ b1_h,
    float* __restrict__ h1)            // ws + 2048
{
    int wave = threadIdx.x >> 6;
    int lane = threadIdx.x & 63;
    int j = blockIdx.x * 4 + wave;
    float si, sg, so;
    gemv3_deep((const f32x4*)fin,
               (const f32x4*)(W1 + (size_t)j * D2),
               (const f32x4*)(W1 + (size_t)(2 * H + j) * D2),
               (const f32x4*)(W1 + (size_t)(3 * H + j) * D2),
               lane, si, sg, so);
    if (lane == 0) {
        float gi = si + b1_i[j] + b1_h[j];
        float gg = sg + b1_i[2 * H + j] + b1_h[2 * H + j];
        float go = so + b1_i[3 * H + j] + b1_h[3 * H + j];
        float c = sigmoidf_(gi) * tanhf(gg);
        h1[j] = sigmoidf_(go) * tanhf(c);
    }
}

// Kernel 3: fc  out[r] = h1 . fc_w[r] + fc_b[r],  r = 0,1
__global__ __launch_bounds__(128) void k_fc(
    const float* __restrict__ h1,     // ws + 2048
    const float* __restrict__ fcw,    // [2][1024]
    const float* __restrict__ fcb,    // [2]
    float* __restrict__ out)          // [2]
{
    int wave = threadIdx.x >> 6;
    int lane = threadIdx.x & 63;
    float s = 0.f;
#pragma unroll
    for (int k = 0; k < 16; ++k) {
        int idx = k * 64 + lane;
        s += h1[idx] * fcw[wave * H + idx];
    }
    s = wave_sum(s);
    if (lane == 0) out[wave] = s + fcb[wave];
}

extern "C" void kernel_launch(void* const* d_in, const int* in_sizes, int n_in,
                              void* d_out, int out_size, void* d_ws, size_t ws_size,
                              hipStream_t stream) {
    const float* goal     = (const float*)d_in[0];
    const float* cur      = (const float*)d_in[1];
    const float* map      = (const float*)d_in[2];
    const float* W_ih_map = (const float*)d_in[3];
    // d_in[4] = W_hh_map  (unused: h0 = 0)
    const float* b_ih_map = (const float*)d_in[5];
    const float* b_hh_map = (const float*)d_in[6];
    const float* W_ih_pts = (const float*)d_in[7];
    // d_in[8] = W_hh_pts  (unused)
    const float* b_ih_pts = (const float*)d_in[9];
    const float* b_hh_pts = (const float*)d_in[10];
    const float* W_ih_1   = (const float*)d_in[11];
    // d_in[12] = W_hh_1   (unused)
    const float* b_ih_1   = (const float*)d_in[13];
    const float* b_hh_1   = (const float*)d_in[14];
    const float* fc_w     = (const float*)d_in[15];
    const float* fc_b     = (const float*)d_in[16];

    float* fin = (float*)d_ws;          // [0..2047] final_in
    float* h1  = (float*)d_ws + 2048;   // [2048..3071] h1
    float* out = (float*)d_out;

    k_first<<<257, 256, 0, stream>>>(map, W_ih_map, b_ih_map, b_hh_map,
                                     W_ih_pts, b_ih_pts, b_hh_pts,
                                     goal, cur, fin);
    k_lstm1<<<256, 256, 0, stream>>>(fin, W_ih_1, b_ih_1, b_hh_1, h1);
    k_fc<<<1, 128, 0, stream>>>(h1, fc_w, fc_b, out);
}